// Round 11
// baseline (225.072 us; speedup 1.0000x reference)
//
#include <hip/hip_runtime.h>

typedef _Float16 half8 __attribute__((ext_vector_type(8)));
typedef _Float16 half4 __attribute__((ext_vector_type(4)));
typedef float f32x4 __attribute__((ext_vector_type(4)));

// Problem constants
#define N_TOK 65536
#define DIM   256
#define KCODE 1024
#define MU_C  0.01f
#define EPS_C 1e-5f

// d_out offsets (floats), reference return order
#define O_Q    0
#define O_LOSS 16777216
#define O_IDX  16777217
#define O_PERP 16842753
#define O_NC   16842754
#define O_NEW  16843778
#define O_EMB  17105922
// NOTE: Xh (f16 copy of X, 32 MB) temporarily lives in out[O_Q..): written by
// k_convert, read by argmin_mfma, overwritten by merge_q / cleanup_write.

// d_ws offsets (4-byte words)
#define W_IDX   0         // int[65536]
#define W_CNT   65536     // u32[1024]
#define W_CUR   66560     // u32[1024]
#define W_OFF   67584     // u32[1024]
#define W_CNTF  68608     // float[1024]
#define W_NFLAG 69632     // u32[1]
#define W_FLAG  69696     // int[65536]
#define W_ORDER 135232    // u32[65536] packed (code<<16)|token
#define W_DW    200768    // float[262144]
#define W_WSQ   462912    // float[1024]
#define W_WH    463936    // _Float16[262144] = 131072 words
#define W_XSQ   595008    // float[65536]  xsq for ALL tokens (by token id)
#define W_ELATA 660544    // float[16384]  per-block e_latent partials
#define W_PACK  676928    // u64[65536] = 131072 words
#define W_HALF  808000    // u64[131072] = 262144 words (two top-2 halves)
// total: 1070144 words = 4.28 MB

__device__ __forceinline__ int imin(int a, int b) { return a < b ? a : b; }
__device__ __forceinline__ int imax(int a, int b) { return a > b ? a : b; }

// ---- fused: W->f16 + wsq, X->f16 (into d_out Q region) + xsq, scratch init
__global__ void k_convert(const float* __restrict__ W, const float* __restrict__ X,
                          _Float16* __restrict__ Wh, _Float16* __restrict__ XhO,
                          float* __restrict__ wsq, float* __restrict__ xsq,
                          unsigned* __restrict__ wsu) {
    int gid = blockIdx.x * 256 + threadIdx.x;
    if (gid < 4097) wsu[W_CNT + gid] = 0u;                      // cnt,cur,offs,cntf,nflag
    if (gid < 65536) {
        ((float4*)(wsu + W_DW))[gid] = make_float4(0.f, 0.f, 0.f, 0.f);
        ((unsigned long long*)(wsu + W_PACK))[gid] = ~0ull;
    }
    int row  = blockIdx.x * 4 + (threadIdx.x >> 6);             // 66560 rows
    int lane = threadIdx.x & 63;
    const float* src;
    _Float16*    dst;
    if (row < KCODE) { src = W + (size_t)row * 256;            dst = Wh  + (size_t)row * 256; }
    else             { src = X + (size_t)(row - KCODE) * 256;  dst = XhO + (size_t)(row - KCODE) * 256; }
    float4 v = *(const float4*)(src + lane * 4);
    half4 h;
    h[0] = (_Float16)v.x; h[1] = (_Float16)v.y; h[2] = (_Float16)v.z; h[3] = (_Float16)v.w;
    *(half4*)(dst + lane * 4) = h;
    float s = v.x * v.x + v.y * v.y + v.z * v.z + v.w * v.w;
#pragma unroll
    for (int off = 1; off < 64; off <<= 1) s += __shfl_xor(s, off);
    if (lane == 0) {
        if (row < KCODE) wsq[row] = s;
        else             xsq[row - KCODE] = s;
    }
}

// ------------------------------------------------------------- argmin via MFMA
// Block = 256 tokens x 512 codes (blockIdx&1 picks half); 4 waves x 64 rows.
// 2-phase counted-vmcnt double buffer; frozen at its structural ceiling.
__global__ __launch_bounds__(256, 2) void argmin_mfma(
    const _Float16* __restrict__ Xh, const _Float16* __restrict__ Wh,
    const float* __restrict__ wsq, unsigned long long* __restrict__ halfres)
{
    __shared__ _Float16 Bs[2][32 * 256];   // 2 x 16 KB

    const int tid  = threadIdx.x;
    const int lane = tid & 63;
    const int w    = tid >> 6;
    const int l15  = lane & 15;
    const int lk   = lane >> 4;
    const int half  = blockIdx.x & 1;
    const int cbase = half * 512;
    const int t0    = (blockIdx.x >> 1) * 256;

    half8 a[4][8];
#pragma unroll
    for (int g2 = 0; g2 < 4; ++g2) {
        const _Float16* xr = Xh + (size_t)(t0 + w * 64 + g2 * 16 + l15) * 256 + lk * 8;
#pragma unroll
        for (int g = 0; g < 8; ++g)
            a[g2][g] = *(const half8*)(xr + g * 32);
    }

    int u1a[16], u2a[16];
#pragma unroll
    for (int i = 0; i < 16; ++i) { u1a[i] = 0x7FFFFFFF; u2a[i] = 0x7FFFFFFF; }

#define STAGE(cc, bb)                                                          \
    _Pragma("unroll")                                                          \
    for (int i = 0; i < 4; ++i) {                                              \
        int loff = (w * 4 + i) * 1024;                                         \
        int off  = loff + lane * 16;                                           \
        int row  = off >> 9;                                                   \
        int slot = (off >> 4) & 31;                                            \
        const _Float16* src = Wh + (size_t)(cbase + (cc) * 32 + row) * 256     \
                                 + ((slot ^ row) << 3);                        \
        __builtin_amdgcn_global_load_lds(                                      \
            (const __attribute__((address_space(1))) void*)src,                \
            (__attribute__((address_space(3))) void*)((char*)Bs[bb] + loff),   \
            16, 0, 0);                                                         \
    }

    STAGE(0, 0);

    for (int c = 0; c < 16; ++c) {
        const int cur = c & 1;
        if (c < 15) {
            STAGE(c + 1, cur ^ 1);
            asm volatile("s_waitcnt vmcnt(4)" ::: "memory");
        } else {
            asm volatile("s_waitcnt vmcnt(0)" ::: "memory");
        }
        __builtin_amdgcn_s_barrier();

        f32x4 acc[4][2];
#pragma unroll
        for (int g2 = 0; g2 < 4; ++g2) { acc[g2][0] = (f32x4)0.0f; acc[g2][1] = (f32x4)0.0f; }

        __builtin_amdgcn_s_setprio(1);
#pragma unroll
        for (int ks = 0; ks < 8; ++ks) {
            const int j = ks * 4 + lk;
            const char* base = (const char*)Bs[cur];
            half8 b0 = *(const half8*)(base + l15 * 512        + ((j ^ l15) << 4));
            half8 b1 = *(const half8*)(base + (16 + l15) * 512 + ((j ^ (16 + l15)) << 4));
#pragma unroll
            for (int g2 = 0; g2 < 4; ++g2) {
                acc[g2][0] = __builtin_amdgcn_mfma_f32_16x16x32_f16(
                    a[g2][ks], b0, acc[g2][0], 0, 0, 0);
                acc[g2][1] = __builtin_amdgcn_mfma_f32_16x16x32_f16(
                    a[g2][ks], b1, acc[g2][1], 0, 0, 0);
            }
        }
        __builtin_amdgcn_s_setprio(0);

#pragma unroll
        for (int nf = 0; nf < 2; ++nf) {
            int   code = cbase + c * 32 + nf * 16 + l15;
            float tc   = fmaf(0.5f, wsq[code], 512.0f);
#pragma unroll
            for (int g2 = 0; g2 < 4; ++g2)
#pragma unroll
                for (int r = 0; r < 4; ++r) {
                    float sv = tc - acc[g2][nf][r];
                    int u = (__float_as_int(sv) & 0xFFFFFC00) | code;
                    int s = g2 * 4 + r;
                    u2a[s] = imin(u2a[s], imax(u1a[s], u));
                    u1a[s] = imin(u1a[s], u);
                }
        }
        __builtin_amdgcn_s_barrier();
    }
#undef STAGE

#pragma unroll
    for (int s = 0; s < 16; ++s) {
#pragma unroll
        for (int off = 1; off < 16; off <<= 1) {
            int b1 = __shfl_xor(u1a[s], off);
            int b2 = __shfl_xor(u2a[s], off);
            int n2 = imin(imin(u2a[s], b2), imax(u1a[s], b1));
            u1a[s] = imin(u1a[s], b1);
            u2a[s] = n2;
        }
    }
    if (l15 == 0) {
#pragma unroll
        for (int s = 0; s < 16; ++s) {
            int row = t0 + w * 64 + (s >> 2) * 16 + lk * 4 + (s & 3);
            halfres[(size_t)half * 65536 + row] =
                ((unsigned long long)(unsigned)u1a[s] << 32) | (unsigned)u2a[s];
        }
    }
}

// ---- merge halves + idx + histogram + flag + token-ordered Q write + e-loss.
// Streaming: X read coalesced, Q written coalesced, W rows gathered from L2,
// halfres broadcast (64 lanes/token share the load).
__global__ __launch_bounds__(256) void merge_q(
    const unsigned long long* __restrict__ halfres,
    const float* __restrict__ X, const float* __restrict__ W,
    int* __restrict__ idx_out, float* __restrict__ out,
    unsigned* __restrict__ cnt, unsigned* __restrict__ nflag,
    int* __restrict__ flaglist, float* __restrict__ elat_arr)
{
    int gid = blockIdx.x * 256 + threadIdx.x;
    int t = gid >> 6, q = gid & 63;
    unsigned long long A = halfres[t], B = halfres[65536 + t];
    int a1 = (int)(A >> 32), a2 = (int)(unsigned)A;
    int b1 = (int)(B >> 32), b2 = (int)(unsigned)B;
    int u1 = imin(a1, b1);
    int u2 = imin(imax(a1, b1), imin(a2, b2));
    int code = u1 & 1023;
    float4 x4 = ((const float4*)X)[gid];
    float4 w4 = *(const float4*)(W + (size_t)code * 256 + q * 4);
    ((float4*)(out + O_Q))[gid] = w4;
    float d0 = w4.x - x4.x, d1 = w4.y - x4.y, d2 = w4.z - x4.z, d3 = w4.w - x4.w;
    float e = d0 * d0 + d1 * d1 + d2 * d2 + d3 * d3;
    if (q == 0) {
        idx_out[t] = code;
        out[O_IDX + t] = (float)code;
        atomicAdd(&cnt[code], 1u);
        float s1 = __int_as_float(u1 & 0xFFFFFC00);
        float s2 = __int_as_float(u2 & 0xFFFFFC00);
        if (s2 - s1 < 0.125f) {
            unsigned p = atomicAdd(nflag, 1u);
            flaglist[p] = t;
        }
    }
#pragma unroll
    for (int off = 1; off < 64; off <<= 1) e += __shfl_xor(e, off);
    __shared__ float se[4];
    int lane = threadIdx.x & 63, wid = threadIdx.x >> 6;
    if (lane == 0) se[wid] = e;
    __syncthreads();
    if (threadIdx.x == 0) elat_arr[blockIdx.x] = se[0] + se[1] + se[2] + se[3];
}

// ------------- exact fp32 re-scoring, 64-token x 128-code blocks, reg-prefetch
__global__ __launch_bounds__(256, 2) void cleanup_gemm(
    const float* __restrict__ X, const float* __restrict__ W,
    const float* __restrict__ wsq, const unsigned* __restrict__ nflagp,
    const int* __restrict__ flaglist, const float* __restrict__ xsq_all,
    unsigned long long* __restrict__ pack)
{
    __shared__ float xs [16][64];
    __shared__ float wps[16][128];
    __shared__ float wsq_s[128];

    const int n = (int)nflagp[0];
    const int tid = threadIdx.x;
    const int tx  = tid & 15;
    const int ty  = tid >> 4;
    const int c0    = (blockIdx.x & 7) * 128;
    const int tslot = blockIdx.x >> 3;
    const int srow_x = tid & 63,  sq_x = tid >> 6;
    const int srow_w = tid & 127, sh_w = tid >> 7;

    if (tid < 128) wsq_s[tid] = wsq[c0 + tid];

    for (int tile = tslot; tile * 64 < n; tile += 256) {
        const int t0 = tile * 64;
        const int gtok = flaglist[imin(t0 + srow_x, n - 1)];
        const float* xrow = X + (size_t)gtok * DIM;
        const float* wrow = W + (size_t)(c0 + srow_w) * DIM + sh_w * 8;

        float xsq_r[4];
#pragma unroll
        for (int i = 0; i < 4; ++i)
            xsq_r[i] = xsq_all[flaglist[imin(t0 + ty * 4 + i, n - 1)]];

        float minv[4]; int mini[4];
#pragma unroll
        for (int i = 0; i < 4; ++i) { minv[i] = 3.402823466e+38f; mini[i] = 0; }

        float acc[4][8];
#pragma unroll
        for (int i = 0; i < 4; ++i)
#pragma unroll
            for (int j = 0; j < 8; ++j) acc[i][j] = 0.0f;

        float4 xa = *(const float4*)(xrow + sq_x * 4);
        float4 wa = *(const float4*)(wrow);
        float4 wb = *(const float4*)(wrow + 4);

        for (int ks = 0; ks < 16; ++ks) {
            __syncthreads();
            xs[sq_x * 4 + 0][srow_x] = xa.x; xs[sq_x * 4 + 1][srow_x] = xa.y;
            xs[sq_x * 4 + 2][srow_x] = xa.z; xs[sq_x * 4 + 3][srow_x] = xa.w;
            wps[sh_w * 8 + 0][srow_w] = wa.x; wps[sh_w * 8 + 1][srow_w] = wa.y;
            wps[sh_w * 8 + 2][srow_w] = wa.z; wps[sh_w * 8 + 3][srow_w] = wa.w;
            wps[sh_w * 8 + 4][srow_w] = wb.x; wps[sh_w * 8 + 5][srow_w] = wb.y;
            wps[sh_w * 8 + 6][srow_w] = wb.z; wps[sh_w * 8 + 7][srow_w] = wb.w;
            __syncthreads();
            if (ks < 15) {
                xa = *(const float4*)(xrow + (ks + 1) * 16 + sq_x * 4);
                wa = *(const float4*)(wrow + (ks + 1) * 16);
                wb = *(const float4*)(wrow + (ks + 1) * 16 + 4);
            }
#pragma unroll
            for (int kl = 0; kl < 16; ++kl) {
                float4 av = *(const float4*)&xs [kl][ty * 4];
                float4 b0 = *(const float4*)&wps[kl][tx * 8];
                float4 b1 = *(const float4*)&wps[kl][tx * 8 + 4];
                float aa[4] = {av.x, av.y, av.z, av.w};
                float bb[8] = {b0.x, b0.y, b0.z, b0.w, b1.x, b1.y, b1.z, b1.w};
#pragma unroll
                for (int i = 0; i < 4; ++i)
#pragma unroll
                    for (int j = 0; j < 8; ++j)
                        acc[i][j] = fmaf(aa[i], bb[j], acc[i][j]);
            }
        }
#pragma unroll
        for (int i = 0; i < 4; ++i) {
#pragma unroll
            for (int j = 0; j < 8; ++j) {
                float t1 = xsq_r[i] + wsq_s[tx * 8 + j];
                float s  = t1 - 2.0f * acc[i][j];
                int   cc = c0 + tx * 8 + j;
                if (s < minv[i]) { minv[i] = s; mini[i] = cc; }
            }
        }
#pragma unroll
        for (int i = 0; i < 4; ++i) {
#pragma unroll
            for (int off = 1; off < 16; off <<= 1) {
                float ov = __shfl_xor(minv[i], off);
                int   oi = __shfl_xor(mini[i], off);
                if (ov < minv[i] || (ov == minv[i] && oi < mini[i])) {
                    minv[i] = ov; mini[i] = oi;
                }
            }
        }
        if (tx == 0) {
#pragma unroll
            for (int i = 0; i < 4; ++i) {
                int pos = t0 + ty * 4 + i;
                if (pos < n) {
                    unsigned long long pu =
                        ((unsigned long long)(unsigned)__float_as_int(minv[i]) << 32)
                        | (unsigned)mini[i];
                    atomicMin(&pack[pos], pu);
                }
            }
        }
        __syncthreads();
    }
}

// ---- wave-per-flag: apply exact result. For CHANGED tokens: fix idx/fidx,
// hist delta, rewrite the Q row, and atomically add the e-loss delta.
__global__ void cleanup_write(const unsigned* __restrict__ nflagp,
                              const int* __restrict__ flaglist,
                              const unsigned long long* __restrict__ pack,
                              const float* __restrict__ X, const float* __restrict__ W,
                              int* __restrict__ idx_out, float* __restrict__ out,
                              unsigned* __restrict__ cnt, float* __restrict__ elat_arr) {
    int n = (int)nflagp[0];
    int wv   = (blockIdx.x * 256 + threadIdx.x) >> 6;   // 1024 waves
    int lane = threadIdx.x & 63;
    for (int i = wv; i < n; i += 1024) {
        int t = flaglist[i];
        int code = (int)(pack[i] & 0xFFFFFFFFull);
        int old  = idx_out[t];
        if (code != old) {
            float4 x4 = *(const float4*)(X + (size_t)t * 256 + lane * 4);
            float4 wn = *(const float4*)(W + (size_t)code * 256 + lane * 4);
            float4 wo = *(const float4*)(W + (size_t)old * 256 + lane * 4);
            ((float4*)(out + O_Q))[(size_t)t * 64 + lane] = wn;
            float n0 = wn.x - x4.x, n1 = wn.y - x4.y, n2 = wn.z - x4.z, n3 = wn.w - x4.w;
            float o0 = wo.x - x4.x, o1 = wo.y - x4.y, o2 = wo.z - x4.z, o3 = wo.w - x4.w;
            float de = (n0 * n0 + n1 * n1 + n2 * n2 + n3 * n3)
                     - (o0 * o0 + o1 * o1 + o2 * o2 + o3 * o3);
#pragma unroll
            for (int off = 1; off < 64; off <<= 1) de += __shfl_xor(de, off);
            if (lane == 0) {
                idx_out[t] = code;
                out[O_IDX + t] = (float)code;
                atomicAdd(&cnt[code], 1u);
                atomicAdd(&cnt[old], 0xFFFFFFFFu);   // -1
                atomicAdd(&elat_arr[0], de);
            }
        }
    }
}

// ------------------------------------------------ scan via wave shuffles
__global__ __launch_bounds__(256) void k_scan(const unsigned* __restrict__ cnt,
                                              unsigned* __restrict__ offs,
                                              float* __restrict__ cntf) {
    int t = threadIdx.x, lane = t & 63, wid = t >> 6;
    uint4 v = ((const uint4*)cnt)[t];
    cntf[4 * t + 0] = (float)v.x; cntf[4 * t + 1] = (float)v.y;
    cntf[4 * t + 2] = (float)v.z; cntf[4 * t + 3] = (float)v.w;
    unsigned s = v.x + v.y + v.z + v.w;
    unsigned ps = s;
#pragma unroll
    for (int off = 1; off < 64; off <<= 1) {
        unsigned o = __shfl_up(ps, off);
        if (lane >= off) ps += o;
    }
    __shared__ unsigned wsum[4];
    if (lane == 63) wsum[wid] = ps;
    __syncthreads();
    unsigned base = 0;
#pragma unroll
    for (int i = 0; i < 4; ++i) if (i < wid) base += wsum[i];
    unsigned excl = base + ps - s;
    offs[4 * t + 0] = excl;
    offs[4 * t + 1] = excl + v.x;
    offs[4 * t + 2] = excl + v.x + v.y;
    offs[4 * t + 3] = excl + v.x + v.y + v.z;
}

// -------------------------------- scatter token ids sorted by code (packed)
__global__ void k_scatter(const int* __restrict__ idx, const unsigned* __restrict__ offs,
                          unsigned* __restrict__ cursor, unsigned* __restrict__ order) {
    int t = blockIdx.x * 256 + threadIdx.x;
    int c = idx[t];
    unsigned p = atomicAdd(&cursor[c], 1u);
    order[offs[c] + p] = ((unsigned)c << 16) | (unsigned)t;
}

// ---- dw only, over sorted order (R8-proven 16/wave form). X is L3-warm.
__global__ __launch_bounds__(256) void k_dw(
    const float* __restrict__ X, const unsigned* __restrict__ order,
    float* __restrict__ dw)
{
    int gw   = (blockIdx.x * 256 + threadIdx.x) >> 6;   // 4096 waves
    int lane = threadIdx.x & 63;
    int p0 = gw * 16;
    float4 acc = make_float4(0.f, 0.f, 0.f, 0.f);
    int cur = -1;
#pragma unroll 4
    for (int i = 0; i < 16; ++i) {
        unsigned u = order[p0 + i];
        int t = (int)(u & 0xFFFFu), c = (int)(u >> 16);
        float4 x4 = *(const float4*)(X + (size_t)t * 256 + lane * 4);
        if (c != cur) {                   // wave-uniform branch
            if (cur >= 0) {
                float* dwp = dw + (size_t)cur * 256 + lane * 4;
                atomicAdd(dwp + 0, acc.x); atomicAdd(dwp + 1, acc.y);
                atomicAdd(dwp + 2, acc.z); atomicAdd(dwp + 3, acc.w);
            }
            cur = c; acc = x4;
        } else {
            acc.x += x4.x; acc.y += x4.y; acc.z += x4.z; acc.w += x4.w;
        }
    }
    if (cur >= 0) {
        float* dwp = dw + (size_t)cur * 256 + lane * 4;
        atomicAdd(dwp + 0, acc.x); atomicAdd(dwp + 1, acc.y);
        atomicAdd(dwp + 2, acc.z); atomicAdd(dwp + 3, acc.w);
    }
}

// ------------------------------------------------ cluster EMA + loss + perplexity
__global__ __launch_bounds__(1024) void finalize_small(
    const float* __restrict__ ecs, const float* __restrict__ counts,
    const float* __restrict__ elat_arr, float* __restrict__ out)
{
    int k = threadIdx.x;
    float cnt = counts[k];
    float nc = ecs[k] * (1.0f - MU_C) + MU_C * cnt;
    float p = cnt * (1.0f / 65536.0f);
    float h = p * logf(p + 1e-10f);
    float el = 0.f;
#pragma unroll
    for (int i = 0; i < 16; ++i) el += elat_arr[k + i * 1024];   // 16384 partials
    float rn = nc, rh = h, re = el;
#pragma unroll
    for (int off = 1; off < 64; off <<= 1) {
        rn += __shfl_xor(rn, off);
        rh += __shfl_xor(rh, off);
        re += __shfl_xor(re, off);
    }
    __shared__ float sn[16], sh[16], sef[16];
    int wid = k >> 6, lane = k & 63;
    if (lane == 0) { sn[wid] = rn; sh[wid] = rh; sef[wid] = re; }
    __syncthreads();
    float n = 0.0f, H = 0.0f, E = 0.0f;
#pragma unroll
    for (int i = 0; i < 16; ++i) { n += sn[i]; H += sh[i]; E += sef[i]; }
    out[O_NC + k] = (nc + EPS_C) / (n + 1024.0f * EPS_C) * n;
    if (k == 0) {
        out[O_LOSS] = 0.25f * (E * (1.0f / 16777216.0f));
        out[O_PERP] = expf(-H);
    }
}

// ------------------------------------------------ new_ema_w / new_embedding
__global__ void finalize_embed(const float* __restrict__ ema_w,
                               const float* __restrict__ dw, float* __restrict__ out)
{
    int gid = blockIdx.x * blockDim.x + threadIdx.x;   // < 262144
    int k = gid >> 8;
    float ew = ema_w[gid] * (1.0f - MU_C) + MU_C * dw[gid];
    out[O_NEW + gid] = ew;
    out[O_EMB + gid] = ew / out[O_NC + k];
}

extern "C" void kernel_launch(void* const* d_in, const int* in_sizes, int n_in,
                              void* d_out, int out_size, void* d_ws, size_t ws_size,
                              hipStream_t stream) {
    const float* X     = (const float*)d_in[0];
    const float* W     = (const float*)d_in[1];
    const float* ema_w = (const float*)d_in[2];
    const float* ecs   = (const float*)d_in[3];
    float*    out    = (float*)d_out;
    unsigned* wsu    = (unsigned*)d_ws;
    float*    wsf    = (float*)d_ws;
    int*      idx    = (int*)d_ws + W_IDX;
    unsigned* cnt    = wsu + W_CNT;
    unsigned* cursor = wsu + W_CUR;
    unsigned* offs   = wsu + W_OFF;
    float*    cntf   = wsf + W_CNTF;
    unsigned* nflag  = wsu + W_NFLAG;
    int*      flags  = (int*)d_ws + W_FLAG;
    unsigned* order  = wsu + W_ORDER;
    float*    dw     = wsf + W_DW;
    float*    wsq    = wsf + W_WSQ;
    _Float16* Wh     = (_Float16*)(wsu + W_WH);
    float*    xsq    = wsf + W_XSQ;
    float*    elatA  = wsf + W_ELATA;
    unsigned long long* pack    = (unsigned long long*)(wsu + W_PACK);
    unsigned long long* halfres = (unsigned long long*)(wsu + W_HALF);
    _Float16* XhO    = (_Float16*)(out + O_Q);   // Xh overlay in Q region

    hipLaunchKernelGGL(k_convert,      dim3(16640), dim3(256),  0, stream, W, X, Wh, XhO, wsq, xsq, wsu);
    hipLaunchKernelGGL(argmin_mfma,    dim3(512),   dim3(256),  0, stream, XhO, Wh, wsq, halfres);
    hipLaunchKernelGGL(merge_q,        dim3(16384), dim3(256),  0, stream, halfres, X, W, idx, out, cnt, nflag, flags, elatA);
    hipLaunchKernelGGL(cleanup_gemm,   dim3(2048),  dim3(256),  0, stream, X, W, wsq, nflag, flags, xsq, pack);
    hipLaunchKernelGGL(cleanup_write,  dim3(256),   dim3(256),  0, stream, nflag, flags, pack, X, W, idx, out, cnt, elatA);
    hipLaunchKernelGGL(k_scan,         dim3(1),     dim3(256),  0, stream, cnt, offs, cntf);
    hipLaunchKernelGGL(k_scatter,      dim3(256),   dim3(256),  0, stream, idx, offs, cursor, order);
    hipLaunchKernelGGL(k_dw,           dim3(1024),  dim3(256),  0, stream, X, order, dw);
    hipLaunchKernelGGL(finalize_small, dim3(1),     dim3(1024), 0, stream, ecs, cntf, elatA, out);
    hipLaunchKernelGGL(finalize_embed, dim3(1024),  dim3(256),  0, stream, ema_w, dw, out);
}

// Round 12
// 214.638 us; speedup vs baseline: 1.0486x; 1.0486x over previous
//
#include <hip/hip_runtime.h>

typedef _Float16 half8 __attribute__((ext_vector_type(8)));
typedef _Float16 half4 __attribute__((ext_vector_type(4)));
typedef float f32x4 __attribute__((ext_vector_type(4)));

// Problem constants
#define N_TOK 65536
#define DIM   256
#define KCODE 1024
#define MU_C  0.01f
#define EPS_C 1e-5f

// d_out offsets (floats), reference return order
#define O_Q    0
#define O_LOSS 16777216
#define O_IDX  16777217
#define O_PERP 16842753
#define O_NC   16842754
#define O_NEW  16843778
#define O_EMB  17105922
// NOTE: Xh (f16 copy of X, 32 MB) temporarily lives in out[O_Q..): written by
// k_convert, read by argmin_mfma, overwritten by k_epilogue_dw.

// d_ws offsets (4-byte words)
#define W_IDX   0         // int[65536]
#define W_CNT   65536     // u32[1024]
#define W_CUR   66560     // u32[1024]
#define W_OFF   67584     // u32[1024]
#define W_CNTF  68608     // float[1024]
#define W_NFLAG 69632     // u32[1]
#define W_FLAG  69696     // int[65536]
#define W_ORDER 135232    // u32[65536] packed (code<<16)|token
#define W_DW    200768    // float[262144]
#define W_WSQ   462912    // float[1024]
#define W_WH    463936    // _Float16[262144] = 131072 words
#define W_XSQ   595008    // float[65536]  xsq for ALL tokens (by token id)
#define W_ELATA 660544    // float[1024]
#define W_PACK  676928    // u64[65536] = 131072 words
#define W_HALF  808000    // u64[131072] = 262144 words (two top-2 halves)
// total: 1070144 words = 4.28 MB

__device__ __forceinline__ int imin(int a, int b) { return a < b ? a : b; }
__device__ __forceinline__ int imax(int a, int b) { return a > b ? a : b; }

// ---- fused: W->f16 + wsq, X->f16 (into d_out Q region) + xsq, scratch init
__global__ void k_convert(const float* __restrict__ W, const float* __restrict__ X,
                          _Float16* __restrict__ Wh, _Float16* __restrict__ XhO,
                          float* __restrict__ wsq, float* __restrict__ xsq,
                          unsigned* __restrict__ wsu) {
    int gid = blockIdx.x * 256 + threadIdx.x;
    if (gid < 4097) wsu[W_CNT + gid] = 0u;                      // cnt,cur,offs,cntf,nflag
    if (gid < 65536) {
        ((float4*)(wsu + W_DW))[gid] = make_float4(0.f, 0.f, 0.f, 0.f);
        ((unsigned long long*)(wsu + W_PACK))[gid] = ~0ull;
    }
    int row  = blockIdx.x * 4 + (threadIdx.x >> 6);             // 66560 rows
    int lane = threadIdx.x & 63;
    const float* src;
    _Float16*    dst;
    if (row < KCODE) { src = W + (size_t)row * 256;            dst = Wh  + (size_t)row * 256; }
    else             { src = X + (size_t)(row - KCODE) * 256;  dst = XhO + (size_t)(row - KCODE) * 256; }
    float4 v = *(const float4*)(src + lane * 4);
    half4 h;
    h[0] = (_Float16)v.x; h[1] = (_Float16)v.y; h[2] = (_Float16)v.z; h[3] = (_Float16)v.w;
    *(half4*)(dst + lane * 4) = h;
    float s = v.x * v.x + v.y * v.y + v.z * v.z + v.w * v.w;
#pragma unroll
    for (int off = 1; off < 64; off <<= 1) s += __shfl_xor(s, off);
    if (lane == 0) {
        if (row < KCODE) wsq[row] = s;
        else             xsq[row - KCODE] = s;
    }
}

// ------------------------------------------------------------- argmin via MFMA
// Block = 256 tokens x 512 codes (blockIdx&1 picks half); 4 waves x 64 rows.
// 2-phase counted-vmcnt double buffer; frozen at its structural ceiling.
__global__ __launch_bounds__(256, 2) void argmin_mfma(
    const _Float16* __restrict__ Xh, const _Float16* __restrict__ Wh,
    const float* __restrict__ wsq, unsigned long long* __restrict__ halfres)
{
    __shared__ _Float16 Bs[2][32 * 256];   // 2 x 16 KB

    const int tid  = threadIdx.x;
    const int lane = tid & 63;
    const int w    = tid >> 6;
    const int l15  = lane & 15;
    const int lk   = lane >> 4;
    const int half  = blockIdx.x & 1;
    const int cbase = half * 512;
    const int t0    = (blockIdx.x >> 1) * 256;

    half8 a[4][8];
#pragma unroll
    for (int g2 = 0; g2 < 4; ++g2) {
        const _Float16* xr = Xh + (size_t)(t0 + w * 64 + g2 * 16 + l15) * 256 + lk * 8;
#pragma unroll
        for (int g = 0; g < 8; ++g)
            a[g2][g] = *(const half8*)(xr + g * 32);
    }

    int u1a[16], u2a[16];
#pragma unroll
    for (int i = 0; i < 16; ++i) { u1a[i] = 0x7FFFFFFF; u2a[i] = 0x7FFFFFFF; }

#define STAGE(cc, bb)                                                          \
    _Pragma("unroll")                                                          \
    for (int i = 0; i < 4; ++i) {                                              \
        int loff = (w * 4 + i) * 1024;                                         \
        int off  = loff + lane * 16;                                           \
        int row  = off >> 9;                                                   \
        int slot = (off >> 4) & 31;                                            \
        const _Float16* src = Wh + (size_t)(cbase + (cc) * 32 + row) * 256     \
                                 + ((slot ^ row) << 3);                        \
        __builtin_amdgcn_global_load_lds(                                      \
            (const __attribute__((address_space(1))) void*)src,                \
            (__attribute__((address_space(3))) void*)((char*)Bs[bb] + loff),   \
            16, 0, 0);                                                         \
    }

    STAGE(0, 0);

    for (int c = 0; c < 16; ++c) {
        const int cur = c & 1;
        if (c < 15) {
            STAGE(c + 1, cur ^ 1);
            asm volatile("s_waitcnt vmcnt(4)" ::: "memory");
        } else {
            asm volatile("s_waitcnt vmcnt(0)" ::: "memory");
        }
        __builtin_amdgcn_s_barrier();

        f32x4 acc[4][2];
#pragma unroll
        for (int g2 = 0; g2 < 4; ++g2) { acc[g2][0] = (f32x4)0.0f; acc[g2][1] = (f32x4)0.0f; }

        __builtin_amdgcn_s_setprio(1);
#pragma unroll
        for (int ks = 0; ks < 8; ++ks) {
            const int j = ks * 4 + lk;
            const char* base = (const char*)Bs[cur];
            half8 b0 = *(const half8*)(base + l15 * 512        + ((j ^ l15) << 4));
            half8 b1 = *(const half8*)(base + (16 + l15) * 512 + ((j ^ (16 + l15)) << 4));
#pragma unroll
            for (int g2 = 0; g2 < 4; ++g2) {
                acc[g2][0] = __builtin_amdgcn_mfma_f32_16x16x32_f16(
                    a[g2][ks], b0, acc[g2][0], 0, 0, 0);
                acc[g2][1] = __builtin_amdgcn_mfma_f32_16x16x32_f16(
                    a[g2][ks], b1, acc[g2][1], 0, 0, 0);
            }
        }
        __builtin_amdgcn_s_setprio(0);

#pragma unroll
        for (int nf = 0; nf < 2; ++nf) {
            int   code = cbase + c * 32 + nf * 16 + l15;
            float tc   = fmaf(0.5f, wsq[code], 512.0f);
#pragma unroll
            for (int g2 = 0; g2 < 4; ++g2)
#pragma unroll
                for (int r = 0; r < 4; ++r) {
                    float sv = tc - acc[g2][nf][r];
                    int u = (__float_as_int(sv) & 0xFFFFFC00) | code;
                    int s = g2 * 4 + r;
                    u2a[s] = imin(u2a[s], imax(u1a[s], u));
                    u1a[s] = imin(u1a[s], u);
                }
        }
        __builtin_amdgcn_s_barrier();
    }
#undef STAGE

#pragma unroll
    for (int s = 0; s < 16; ++s) {
#pragma unroll
        for (int off = 1; off < 16; off <<= 1) {
            int b1 = __shfl_xor(u1a[s], off);
            int b2 = __shfl_xor(u2a[s], off);
            int n2 = imin(imin(u2a[s], b2), imax(u1a[s], b1));
            u1a[s] = imin(u1a[s], b1);
            u2a[s] = n2;
        }
    }
    if (l15 == 0) {
#pragma unroll
        for (int s = 0; s < 16; ++s) {
            int row = t0 + w * 64 + (s >> 2) * 16 + lk * 4 + (s & 3);
            halfres[(size_t)half * 65536 + row] =
                ((unsigned long long)(unsigned)u1a[s] << 32) | (unsigned)u2a[s];
        }
    }
}

// ---- merge halves: write provisional idx, histogram it, flag near-ties
__global__ void merge_halves(const unsigned long long* __restrict__ halfres,
                             int* __restrict__ idx_out, float* __restrict__ out,
                             unsigned* __restrict__ cnt,
                             unsigned* __restrict__ nflag, int* __restrict__ flaglist)
{
    int t = blockIdx.x * 256 + threadIdx.x;
    unsigned long long A = halfres[t], B = halfres[65536 + t];
    int a1 = (int)(A >> 32), a2 = (int)(unsigned)A;
    int b1 = (int)(B >> 32), b2 = (int)(unsigned)B;
    int u1 = imin(a1, b1);
    int u2 = imin(imax(a1, b1), imin(a2, b2));
    int code = u1 & 1023;
    idx_out[t] = code;
    out[O_IDX + t] = (float)code;
    atomicAdd(&cnt[code], 1u);
    float s1 = __int_as_float(u1 & 0xFFFFFC00);
    float s2 = __int_as_float(u2 & 0xFFFFFC00);
    if (s2 - s1 < 0.125f) {
        unsigned p = atomicAdd(nflag, 1u);
        flaglist[p] = t;
    }
}

// ------------- exact fp32 re-scoring, 64-token x 128-code blocks, reg-prefetch
__global__ __launch_bounds__(256, 2) void cleanup_gemm(
    const float* __restrict__ X, const float* __restrict__ W,
    const float* __restrict__ wsq, const unsigned* __restrict__ nflagp,
    const int* __restrict__ flaglist, const float* __restrict__ xsq_all,
    unsigned long long* __restrict__ pack)
{
    __shared__ float xs [16][64];
    __shared__ float wps[16][128];
    __shared__ float wsq_s[128];

    const int n = (int)nflagp[0];
    const int tid = threadIdx.x;
    const int tx  = tid & 15;
    const int ty  = tid >> 4;
    const int c0    = (blockIdx.x & 7) * 128;
    const int tslot = blockIdx.x >> 3;
    const int srow_x = tid & 63,  sq_x = tid >> 6;
    const int srow_w = tid & 127, sh_w = tid >> 7;

    if (tid < 128) wsq_s[tid] = wsq[c0 + tid];

    for (int tile = tslot; tile * 64 < n; tile += 256) {
        const int t0 = tile * 64;
        const int gtok = flaglist[imin(t0 + srow_x, n - 1)];
        const float* xrow = X + (size_t)gtok * DIM;
        const float* wrow = W + (size_t)(c0 + srow_w) * DIM + sh_w * 8;

        float xsq_r[4];
#pragma unroll
        for (int i = 0; i < 4; ++i)
            xsq_r[i] = xsq_all[flaglist[imin(t0 + ty * 4 + i, n - 1)]];

        float minv[4]; int mini[4];
#pragma unroll
        for (int i = 0; i < 4; ++i) { minv[i] = 3.402823466e+38f; mini[i] = 0; }

        float acc[4][8];
#pragma unroll
        for (int i = 0; i < 4; ++i)
#pragma unroll
            for (int j = 0; j < 8; ++j) acc[i][j] = 0.0f;

        float4 xa = *(const float4*)(xrow + sq_x * 4);
        float4 wa = *(const float4*)(wrow);
        float4 wb = *(const float4*)(wrow + 4);

        for (int ks = 0; ks < 16; ++ks) {
            __syncthreads();
            xs[sq_x * 4 + 0][srow_x] = xa.x; xs[sq_x * 4 + 1][srow_x] = xa.y;
            xs[sq_x * 4 + 2][srow_x] = xa.z; xs[sq_x * 4 + 3][srow_x] = xa.w;
            wps[sh_w * 8 + 0][srow_w] = wa.x; wps[sh_w * 8 + 1][srow_w] = wa.y;
            wps[sh_w * 8 + 2][srow_w] = wa.z; wps[sh_w * 8 + 3][srow_w] = wa.w;
            wps[sh_w * 8 + 4][srow_w] = wb.x; wps[sh_w * 8 + 5][srow_w] = wb.y;
            wps[sh_w * 8 + 6][srow_w] = wb.z; wps[sh_w * 8 + 7][srow_w] = wb.w;
            __syncthreads();
            if (ks < 15) {
                xa = *(const float4*)(xrow + (ks + 1) * 16 + sq_x * 4);
                wa = *(const float4*)(wrow + (ks + 1) * 16);
                wb = *(const float4*)(wrow + (ks + 1) * 16 + 4);
            }
#pragma unroll
            for (int kl = 0; kl < 16; ++kl) {
                float4 av = *(const float4*)&xs [kl][ty * 4];
                float4 b0 = *(const float4*)&wps[kl][tx * 8];
                float4 b1 = *(const float4*)&wps[kl][tx * 8 + 4];
                float aa[4] = {av.x, av.y, av.z, av.w};
                float bb[8] = {b0.x, b0.y, b0.z, b0.w, b1.x, b1.y, b1.z, b1.w};
#pragma unroll
                for (int i = 0; i < 4; ++i)
#pragma unroll
                    for (int j = 0; j < 8; ++j)
                        acc[i][j] = fmaf(aa[i], bb[j], acc[i][j]);
            }
        }
#pragma unroll
        for (int i = 0; i < 4; ++i) {
#pragma unroll
            for (int j = 0; j < 8; ++j) {
                float t1 = xsq_r[i] + wsq_s[tx * 8 + j];
                float s  = t1 - 2.0f * acc[i][j];
                int   cc = c0 + tx * 8 + j;
                if (s < minv[i]) { minv[i] = s; mini[i] = cc; }
            }
        }
#pragma unroll
        for (int i = 0; i < 4; ++i) {
#pragma unroll
            for (int off = 1; off < 16; off <<= 1) {
                float ov = __shfl_xor(minv[i], off);
                int   oi = __shfl_xor(mini[i], off);
                if (ov < minv[i] || (ov == minv[i] && oi < mini[i])) {
                    minv[i] = ov; mini[i] = oi;
                }
            }
        }
        if (tx == 0) {
#pragma unroll
            for (int i = 0; i < 4; ++i) {
                int pos = t0 + ty * 4 + i;
                if (pos < n) {
                    unsigned long long pu =
                        ((unsigned long long)(unsigned)__float_as_int(minv[i]) << 32)
                        | (unsigned)mini[i];
                    atomicMin(&pack[pos], pu);
                }
            }
        }
        __syncthreads();
    }
}

// ---- unpack cleanup results; delta-correct idx, float idx, and histogram
__global__ void cleanup_write(const unsigned* __restrict__ nflagp,
                              const int* __restrict__ flaglist,
                              const unsigned long long* __restrict__ pack,
                              int* __restrict__ idx_out, float* __restrict__ out,
                              unsigned* __restrict__ cnt) {
    int n = (int)nflagp[0];
    for (int i = blockIdx.x * 256 + threadIdx.x; i < n; i += 65536) {
        int t = flaglist[i];
        int code = (int)(pack[i] & 0xFFFFFFFFull);
        int old  = idx_out[t];
        if (code != old) {
            idx_out[t] = code;
            out[O_IDX + t] = (float)code;
            atomicAdd(&cnt[code], 1u);
            atomicAdd(&cnt[old], 0xFFFFFFFFu);   // -1
        }
    }
}

// ------------------------------------------------ scan via wave shuffles
__global__ __launch_bounds__(256) void k_scan(const unsigned* __restrict__ cnt,
                                              unsigned* __restrict__ offs,
                                              float* __restrict__ cntf) {
    int t = threadIdx.x, lane = t & 63, wid = t >> 6;
    uint4 v = ((const uint4*)cnt)[t];
    cntf[4 * t + 0] = (float)v.x; cntf[4 * t + 1] = (float)v.y;
    cntf[4 * t + 2] = (float)v.z; cntf[4 * t + 3] = (float)v.w;
    unsigned s = v.x + v.y + v.z + v.w;
    unsigned ps = s;
#pragma unroll
    for (int off = 1; off < 64; off <<= 1) {
        unsigned o = __shfl_up(ps, off);
        if (lane >= off) ps += o;
    }
    __shared__ unsigned wsum[4];
    if (lane == 63) wsum[wid] = ps;
    __syncthreads();
    unsigned base = 0;
#pragma unroll
    for (int i = 0; i < 4; ++i) if (i < wid) base += wsum[i];
    unsigned excl = base + ps - s;
    offs[4 * t + 0] = excl;
    offs[4 * t + 1] = excl + v.x;
    offs[4 * t + 2] = excl + v.x + v.y;
    offs[4 * t + 3] = excl + v.x + v.y + v.z;
}

// -------------------------------- scatter token ids sorted by code (packed)
__global__ void k_scatter(const int* __restrict__ idx, const unsigned* __restrict__ offs,
                          unsigned* __restrict__ cursor, unsigned* __restrict__ order) {
    int t = blockIdx.x * 256 + threadIdx.x;
    int c = idx[t];
    unsigned p = atomicAdd(&cursor[c], 1u);
    order[offs[c] + p] = ((unsigned)c << 16) | (unsigned)t;
}

// ---- fused consumer over sorted order: Q gather-write + e-loss + dw runs.
// R10 form (16 positions/wave, 4096 flushes) with ONE change: all 16 X-row
// loads are issued up-front (independent addresses from wave-uniform order)
// so ~16 HBM loads stay in flight instead of ~4 (R10's unroll-4 chain).
__global__ __launch_bounds__(256) void k_epilogue_dw(
    const float* __restrict__ X, const float* __restrict__ W,
    const unsigned* __restrict__ order, float* __restrict__ out,
    float* __restrict__ dw, float* __restrict__ elat_arr)
{
    int gw   = (blockIdx.x * 256 + threadIdx.x) >> 6;   // 4096 waves
    int lane = threadIdx.x & 63;
    int p0 = gw * 16;
    uint4 oa = *(const uint4*)(order + p0);
    uint4 ob = *(const uint4*)(order + p0 + 4);
    uint4 oc = *(const uint4*)(order + p0 + 8);
    uint4 od = *(const uint4*)(order + p0 + 12);
    unsigned o[16] = {oa.x, oa.y, oa.z, oa.w, ob.x, ob.y, ob.z, ob.w,
                      oc.x, oc.y, oc.z, oc.w, od.x, od.y, od.z, od.w};
    float4 x[16];
#pragma unroll
    for (int i = 0; i < 16; ++i)
        x[i] = *(const float4*)(X + (size_t)(o[i] & 0xFFFFu) * 256 + lane * 4);

    int   cur  = (int)(o[0] >> 16);
    float4 wreg = *(const float4*)(W + (size_t)cur * 256 + lane * 4);
    float4 acc = x[0];
    float e;
    {
        ((float4*)(out + O_Q))[(size_t)(o[0] & 0xFFFFu) * 64 + lane] = wreg;
        float d0 = wreg.x - x[0].x, d1 = wreg.y - x[0].y;
        float d2 = wreg.z - x[0].z, d3 = wreg.w - x[0].w;
        e = d0 * d0 + d1 * d1 + d2 * d2 + d3 * d3;
    }
#pragma unroll
    for (int i = 1; i < 16; ++i) {
        int t = (int)(o[i] & 0xFFFFu), c = (int)(o[i] >> 16);
        if (c != cur) {                   // wave-uniform branch
            float* dwp = dw + (size_t)cur * 256 + lane * 4;
            atomicAdd(dwp + 0, acc.x); atomicAdd(dwp + 1, acc.y);
            atomicAdd(dwp + 2, acc.z); atomicAdd(dwp + 3, acc.w);
            wreg = *(const float4*)(W + (size_t)c * 256 + lane * 4);
            cur = c; acc = x[i];
        } else {
            acc.x += x[i].x; acc.y += x[i].y; acc.z += x[i].z; acc.w += x[i].w;
        }
        ((float4*)(out + O_Q))[(size_t)t * 64 + lane] = wreg;
        float d0 = wreg.x - x[i].x, d1 = wreg.y - x[i].y;
        float d2 = wreg.z - x[i].z, d3 = wreg.w - x[i].w;
        e += d0 * d0 + d1 * d1 + d2 * d2 + d3 * d3;
    }
    {
        float* dwp = dw + (size_t)cur * 256 + lane * 4;
        atomicAdd(dwp + 0, acc.x); atomicAdd(dwp + 1, acc.y);
        atomicAdd(dwp + 2, acc.z); atomicAdd(dwp + 3, acc.w);
    }
#pragma unroll
    for (int off = 1; off < 64; off <<= 1) e += __shfl_xor(e, off);
    __shared__ float se[4];
    int wid = threadIdx.x >> 6;
    if (lane == 0) se[wid] = e;
    __syncthreads();
    if (threadIdx.x == 0) elat_arr[blockIdx.x] = se[0] + se[1] + se[2] + se[3];
}

// ------------------------------------------------ cluster EMA + loss + perplexity
__global__ __launch_bounds__(1024) void finalize_small(
    const float* __restrict__ ecs, const float* __restrict__ counts,
    const float* __restrict__ elat_arr, float* __restrict__ out)
{
    int k = threadIdx.x;
    float cnt = counts[k];
    float nc = ecs[k] * (1.0f - MU_C) + MU_C * cnt;
    float p = cnt * (1.0f / 65536.0f);
    float h = p * logf(p + 1e-10f);
    float el = elat_arr[k];               // 1024 per-block partials
    float rn = nc, rh = h, re = el;
#pragma unroll
    for (int off = 1; off < 64; off <<= 1) {
        rn += __shfl_xor(rn, off);
        rh += __shfl_xor(rh, off);
        re += __shfl_xor(re, off);
    }
    __shared__ float sn[16], sh[16], sef[16];
    int wid = k >> 6, lane = k & 63;
    if (lane == 0) { sn[wid] = rn; sh[wid] = rh; sef[wid] = re; }
    __syncthreads();
    float n = 0.0f, H = 0.0f, E = 0.0f;
#pragma unroll
    for (int i = 0; i < 16; ++i) { n += sn[i]; H += sh[i]; E += sef[i]; }
    out[O_NC + k] = (nc + EPS_C) / (n + 1024.0f * EPS_C) * n;
    if (k == 0) {
        out[O_LOSS] = 0.25f * (E * (1.0f / 16777216.0f));
        out[O_PERP] = expf(-H);
    }
}

// ------------------------------------------------ new_ema_w / new_embedding
__global__ void finalize_embed(const float* __restrict__ ema_w,
                               const float* __restrict__ dw, float* __restrict__ out)
{
    int gid = blockIdx.x * blockDim.x + threadIdx.x;   // < 262144
    int k = gid >> 8;
    float ew = ema_w[gid] * (1.0f - MU_C) + MU_C * dw[gid];
    out[O_NEW + gid] = ew;
    out[O_EMB + gid] = ew / out[O_NC + k];
}

extern "C" void kernel_launch(void* const* d_in, const int* in_sizes, int n_in,
                              void* d_out, int out_size, void* d_ws, size_t ws_size,
                              hipStream_t stream) {
    const float* X     = (const float*)d_in[0];
    const float* W     = (const float*)d_in[1];
    const float* ema_w = (const float*)d_in[2];
    const float* ecs   = (const float*)d_in[3];
    float*    out    = (float*)d_out;
    unsigned* wsu    = (unsigned*)d_ws;
    float*    wsf    = (float*)d_ws;
    int*      idx    = (int*)d_ws + W_IDX;
    unsigned* cnt    = wsu + W_CNT;
    unsigned* cursor = wsu + W_CUR;
    unsigned* offs   = wsu + W_OFF;
    float*    cntf   = wsf + W_CNTF;
    unsigned* nflag  = wsu + W_NFLAG;
    int*      flags  = (int*)d_ws + W_FLAG;
    unsigned* order  = wsu + W_ORDER;
    float*    dw     = wsf + W_DW;
    float*    wsq    = wsf + W_WSQ;
    _Float16* Wh     = (_Float16*)(wsu + W_WH);
    float*    xsq    = wsf + W_XSQ;
    float*    elatA  = wsf + W_ELATA;
    unsigned long long* pack    = (unsigned long long*)(wsu + W_PACK);
    unsigned long long* halfres = (unsigned long long*)(wsu + W_HALF);
    _Float16* XhO    = (_Float16*)(out + O_Q);   // Xh overlay in Q region

    hipLaunchKernelGGL(k_convert,      dim3(16640), dim3(256),  0, stream, W, X, Wh, XhO, wsq, xsq, wsu);
    hipLaunchKernelGGL(argmin_mfma,    dim3(512),   dim3(256),  0, stream, XhO, Wh, wsq, halfres);
    hipLaunchKernelGGL(merge_halves,   dim3(256),   dim3(256),  0, stream, halfres, idx, out, cnt, nflag, flags);
    hipLaunchKernelGGL(cleanup_gemm,   dim3(2048),  dim3(256),  0, stream, X, W, wsq, nflag, flags, xsq, pack);
    hipLaunchKernelGGL(cleanup_write,  dim3(256),   dim3(256),  0, stream, nflag, flags, pack, idx, out, cnt);
    hipLaunchKernelGGL(k_scan,         dim3(1),     dim3(256),  0, stream, cnt, offs, cntf);
    hipLaunchKernelGGL(k_scatter,      dim3(256),   dim3(256),  0, stream, idx, offs, cursor, order);
    hipLaunchKernelGGL(k_epilogue_dw,  dim3(1024),  dim3(256),  0, stream, X, W, order, out, dw, elatA);
    hipLaunchKernelGGL(finalize_small, dim3(1),     dim3(1024), 0, stream, ecs, cntf, elatA, out);
    hipLaunchKernelGGL(finalize_embed, dim3(1024),  dim3(256),  0, stream, ema_w, dw, out);
}

// Round 13
// 210.266 us; speedup vs baseline: 1.0704x; 1.0208x over previous
//
#include <hip/hip_runtime.h>

typedef _Float16 half8 __attribute__((ext_vector_type(8)));
typedef _Float16 half4 __attribute__((ext_vector_type(4)));
typedef float f32x4 __attribute__((ext_vector_type(4)));

// Problem constants
#define N_TOK 65536
#define DIM   256
#define KCODE 1024
#define MU_C  0.01f
#define EPS_C 1e-5f

// d_out offsets (floats), reference return order
#define O_Q    0
#define O_LOSS 16777216
#define O_IDX  16777217
#define O_PERP 16842753
#define O_NC   16842754
#define O_NEW  16843778
#define O_EMB  17105922

// d_ws offsets (4-byte words)
#define W_IDX   0         // int[65536]
#define W_CNT   65536     // u32[1024]
#define W_CUR   66560     // u32[1024]
#define W_OFF   67584     // u32[1024] (unused; kept for layout stability)
#define W_CNTF  68608     // float[1024]
#define W_NFLAG 69632     // u32[1]
#define W_FLAG  69696     // int[65536]
#define W_ORDER 135232    // u32[65536] packed (code<<16)|token
#define W_DW    200768    // float[262144]
#define W_WSQ   462912    // float[1024]
#define W_WH    463936    // _Float16[262144] = 131072 words
#define W_XSQF  595008    // float[65536]  xsq of flagged tokens (compact)
#define W_ELATA 660544    // float[1024]
#define W_PACK  676928    // u64[65536] = 131072 words
#define W_HALF  808000    // u64[131072] = 262144 words (two top-2 halves)
// total: 1070144 words = 4.28 MB

__device__ __forceinline__ int imin(int a, int b) { return a < b ? a : b; }
__device__ __forceinline__ int imax(int a, int b) { return a > b ? a : b; }

// ---- W -> f16 + row sum-of-squares + ALL scratch init (65536 threads)
__global__ void k_init(const float* __restrict__ W, _Float16* __restrict__ Wh,
                       float* __restrict__ wsq, unsigned* __restrict__ wsu) {
    int gid = blockIdx.x * 256 + threadIdx.x;   // 65536
    if (gid < 4097) wsu[W_CNT + gid] = 0u;      // cnt, cursor, offs, cntf, nflag
    ((float4*)(wsu + W_DW))[gid] = make_float4(0.f, 0.f, 0.f, 0.f);   // dw
    ((unsigned long long*)(wsu + W_PACK))[gid] = ~0ull;               // pack
    int row = gid >> 6, lane = gid & 63;        // 1024 W rows
    float4 v = *(const float4*)(W + (size_t)row * 256 + lane * 4);
    half4 h;
    h[0] = (_Float16)v.x; h[1] = (_Float16)v.y; h[2] = (_Float16)v.z; h[3] = (_Float16)v.w;
    *(half4*)(Wh + (size_t)row * 256 + lane * 4) = h;
    float s = v.x * v.x + v.y * v.y + v.z * v.z + v.w * v.w;
#pragma unroll
    for (int off = 1; off < 64; off <<= 1) s += __shfl_xor(s, off);
    if (lane == 0) wsq[row] = s;
}

// ------------------------------------------------------------- argmin via MFMA
// R8-proven form: block = 256 tokens x 512 codes (blockIdx&1 picks half);
// 4 waves x 64 token rows; A loaded f32 + converted in-prologue; B chunks of
// 32 codes double-buffered (2 x 16 KB), counted-vmcnt pipeline.
__global__ __launch_bounds__(256, 2) void argmin_mfma(
    const float* __restrict__ X, const _Float16* __restrict__ Wh,
    const float* __restrict__ wsq, unsigned long long* __restrict__ halfres)
{
    __shared__ _Float16 Bs[2][32 * 256];   // 2 x 16 KB

    const int tid  = threadIdx.x;
    const int lane = tid & 63;
    const int w    = tid >> 6;
    const int l15  = lane & 15;
    const int lk   = lane >> 4;
    const int half  = blockIdx.x & 1;
    const int cbase = half * 512;
    const int t0    = (blockIdx.x >> 1) * 256;

    half8 a[4][8];
#pragma unroll
    for (int g2 = 0; g2 < 4; ++g2) {
        const float* xr = X + (size_t)(t0 + w * 64 + g2 * 16 + l15) * 256 + lk * 8;
#pragma unroll
        for (int g = 0; g < 8; ++g) {
            float4 u0 = *(const float4*)(xr + g * 32);
            float4 u1 = *(const float4*)(xr + g * 32 + 4);
            half8 h;
            h[0] = (_Float16)u0.x; h[1] = (_Float16)u0.y;
            h[2] = (_Float16)u0.z; h[3] = (_Float16)u0.w;
            h[4] = (_Float16)u1.x; h[5] = (_Float16)u1.y;
            h[6] = (_Float16)u1.z; h[7] = (_Float16)u1.w;
            a[g2][g] = h;
        }
    }

    int u1a[16], u2a[16];
#pragma unroll
    for (int i = 0; i < 16; ++i) { u1a[i] = 0x7FFFFFFF; u2a[i] = 0x7FFFFFFF; }

#define STAGE(cc, bb)                                                          \
    _Pragma("unroll")                                                          \
    for (int i = 0; i < 4; ++i) {                                              \
        int loff = (w * 4 + i) * 1024;                                         \
        int off  = loff + lane * 16;                                           \
        int row  = off >> 9;                                                   \
        int slot = (off >> 4) & 31;                                            \
        const _Float16* src = Wh + (size_t)(cbase + (cc) * 32 + row) * 256     \
                                 + ((slot ^ row) << 3);                        \
        __builtin_amdgcn_global_load_lds(                                      \
            (const __attribute__((address_space(1))) void*)src,                \
            (__attribute__((address_space(3))) void*)((char*)Bs[bb] + loff),   \
            16, 0, 0);                                                         \
    }

    STAGE(0, 0);

    for (int c = 0; c < 16; ++c) {
        const int cur = c & 1;
        if (c < 15) {
            STAGE(c + 1, cur ^ 1);
            asm volatile("s_waitcnt vmcnt(4)" ::: "memory");
        } else {
            asm volatile("s_waitcnt vmcnt(0)" ::: "memory");
        }
        __builtin_amdgcn_s_barrier();

        f32x4 acc[4][2];
#pragma unroll
        for (int g2 = 0; g2 < 4; ++g2) { acc[g2][0] = (f32x4)0.0f; acc[g2][1] = (f32x4)0.0f; }

        __builtin_amdgcn_s_setprio(1);
#pragma unroll
        for (int ks = 0; ks < 8; ++ks) {
            const int j = ks * 4 + lk;
            const char* base = (const char*)Bs[cur];
            half8 b0 = *(const half8*)(base + l15 * 512        + ((j ^ l15) << 4));
            half8 b1 = *(const half8*)(base + (16 + l15) * 512 + ((j ^ (16 + l15)) << 4));
#pragma unroll
            for (int g2 = 0; g2 < 4; ++g2) {
                acc[g2][0] = __builtin_amdgcn_mfma_f32_16x16x32_f16(
                    a[g2][ks], b0, acc[g2][0], 0, 0, 0);
                acc[g2][1] = __builtin_amdgcn_mfma_f32_16x16x32_f16(
                    a[g2][ks], b1, acc[g2][1], 0, 0, 0);
            }
        }
        __builtin_amdgcn_s_setprio(0);

#pragma unroll
        for (int nf = 0; nf < 2; ++nf) {
            int   code = cbase + c * 32 + nf * 16 + l15;
            float tc   = fmaf(0.5f, wsq[code], 512.0f);
#pragma unroll
            for (int g2 = 0; g2 < 4; ++g2)
#pragma unroll
                for (int r = 0; r < 4; ++r) {
                    float sv = tc - acc[g2][nf][r];
                    int u = (__float_as_int(sv) & 0xFFFFFC00) | code;
                    int s = g2 * 4 + r;
                    u2a[s] = imin(u2a[s], imax(u1a[s], u));
                    u1a[s] = imin(u1a[s], u);
                }
        }
        __builtin_amdgcn_s_barrier();
    }
#undef STAGE

#pragma unroll
    for (int s = 0; s < 16; ++s) {
#pragma unroll
        for (int off = 1; off < 16; off <<= 1) {
            int b1 = __shfl_xor(u1a[s], off);
            int b2 = __shfl_xor(u2a[s], off);
            int n2 = imin(imin(u2a[s], b2), imax(u1a[s], b1));
            u1a[s] = imin(u1a[s], b1);
            u2a[s] = n2;
        }
    }
    if (l15 == 0) {
#pragma unroll
        for (int s = 0; s < 16; ++s) {
            int row = t0 + w * 64 + (s >> 2) * 16 + lk * 4 + (s & 3);
            halfres[(size_t)half * 65536 + row] =
                ((unsigned long long)(unsigned)u1a[s] << 32) | (unsigned)u2a[s];
        }
    }
}

// ---- merge halves: write provisional idx, histogram it, flag near-ties
__global__ void merge_halves(const unsigned long long* __restrict__ halfres,
                             int* __restrict__ idx_out, float* __restrict__ out,
                             unsigned* __restrict__ cnt,
                             unsigned* __restrict__ nflag, int* __restrict__ flaglist)
{
    int t = blockIdx.x * 256 + threadIdx.x;
    unsigned long long A = halfres[t], B = halfres[65536 + t];
    int a1 = (int)(A >> 32), a2 = (int)(unsigned)A;
    int b1 = (int)(B >> 32), b2 = (int)(unsigned)B;
    int u1 = imin(a1, b1);
    int u2 = imin(imax(a1, b1), imin(a2, b2));
    int code = u1 & 1023;
    idx_out[t] = code;
    out[O_IDX + t] = (float)code;
    atomicAdd(&cnt[code], 1u);
    float s1 = __int_as_float(u1 & 0xFFFFFC00);
    float s2 = __int_as_float(u2 & 0xFFFFFC00);
    if (s2 - s1 < 0.125f) {
        unsigned p = atomicAdd(nflag, 1u);
        flaglist[p] = t;
    }
}

// ------------------------------------ xsq for flagged tokens (compacted array)
__global__ void cleanup_xsq(const float* __restrict__ X,
                            const unsigned* __restrict__ nflagp,
                            const int* __restrict__ flaglist,
                            float* __restrict__ xsqf) {
    int n = (int)nflagp[0];
    int wid  = (blockIdx.x * 256 + threadIdx.x) >> 6;   // 1024 waves
    int lane = threadIdx.x & 63;
    for (int i = wid; i < n; i += 1024) {
        const float* row = X + (size_t)flaglist[i] * 256;
        float4 v = *(const float4*)(row + lane * 4);
        float s = v.x * v.x + v.y * v.y + v.z * v.z + v.w * v.w;
#pragma unroll
        for (int off = 1; off < 64; off <<= 1) s += __shfl_xor(s, off);
        if (lane == 0) xsqf[i] = s;
    }
}

// ------------- exact fp32 re-scoring, 64-token x 128-code blocks, reg-prefetch
__global__ __launch_bounds__(256, 2) void cleanup_gemm(
    const float* __restrict__ X, const float* __restrict__ W,
    const float* __restrict__ wsq, const unsigned* __restrict__ nflagp,
    const int* __restrict__ flaglist, const float* __restrict__ xsqf,
    unsigned long long* __restrict__ pack)
{
    __shared__ float xs [16][64];
    __shared__ float wps[16][128];
    __shared__ float wsq_s[128];

    const int n = (int)nflagp[0];
    const int tid = threadIdx.x;
    const int tx  = tid & 15;
    const int ty  = tid >> 4;
    const int c0    = (blockIdx.x & 7) * 128;
    const int tslot = blockIdx.x >> 3;
    const int srow_x = tid & 63,  sq_x = tid >> 6;
    const int srow_w = tid & 127, sh_w = tid >> 7;

    if (tid < 128) wsq_s[tid] = wsq[c0 + tid];

    for (int tile = tslot; tile * 64 < n; tile += 256) {
        const int t0 = tile * 64;
        const int gtok = flaglist[imin(t0 + srow_x, n - 1)];
        const float* xrow = X + (size_t)gtok * DIM;
        const float* wrow = W + (size_t)(c0 + srow_w) * DIM + sh_w * 8;

        float xsq_r[4];
#pragma unroll
        for (int i = 0; i < 4; ++i) xsq_r[i] = xsqf[imin(t0 + ty * 4 + i, n - 1)];

        float minv[4]; int mini[4];
#pragma unroll
        for (int i = 0; i < 4; ++i) { minv[i] = 3.402823466e+38f; mini[i] = 0; }

        float acc[4][8];
#pragma unroll
        for (int i = 0; i < 4; ++i)
#pragma unroll
            for (int j = 0; j < 8; ++j) acc[i][j] = 0.0f;

        float4 xa = *(const float4*)(xrow + sq_x * 4);
        float4 wa = *(const float4*)(wrow);
        float4 wb = *(const float4*)(wrow + 4);

        for (int ks = 0; ks < 16; ++ks) {
            __syncthreads();
            xs[sq_x * 4 + 0][srow_x] = xa.x; xs[sq_x * 4 + 1][srow_x] = xa.y;
            xs[sq_x * 4 + 2][srow_x] = xa.z; xs[sq_x * 4 + 3][srow_x] = xa.w;
            wps[sh_w * 8 + 0][srow_w] = wa.x; wps[sh_w * 8 + 1][srow_w] = wa.y;
            wps[sh_w * 8 + 2][srow_w] = wa.z; wps[sh_w * 8 + 3][srow_w] = wa.w;
            wps[sh_w * 8 + 4][srow_w] = wb.x; wps[sh_w * 8 + 5][srow_w] = wb.y;
            wps[sh_w * 8 + 6][srow_w] = wb.z; wps[sh_w * 8 + 7][srow_w] = wb.w;
            __syncthreads();
            if (ks < 15) {
                xa = *(const float4*)(xrow + (ks + 1) * 16 + sq_x * 4);
                wa = *(const float4*)(wrow + (ks + 1) * 16);
                wb = *(const float4*)(wrow + (ks + 1) * 16 + 4);
            }
#pragma unroll
            for (int kl = 0; kl < 16; ++kl) {
                float4 av = *(const float4*)&xs [kl][ty * 4];
                float4 b0 = *(const float4*)&wps[kl][tx * 8];
                float4 b1 = *(const float4*)&wps[kl][tx * 8 + 4];
                float aa[4] = {av.x, av.y, av.z, av.w};
                float bb[8] = {b0.x, b0.y, b0.z, b0.w, b1.x, b1.y, b1.z, b1.w};
#pragma unroll
                for (int i = 0; i < 4; ++i)
#pragma unroll
                    for (int j = 0; j < 8; ++j)
                        acc[i][j] = fmaf(aa[i], bb[j], acc[i][j]);
            }
        }
#pragma unroll
        for (int i = 0; i < 4; ++i) {
#pragma unroll
            for (int j = 0; j < 8; ++j) {
                float t1 = xsq_r[i] + wsq_s[tx * 8 + j];
                float s  = t1 - 2.0f * acc[i][j];
                int   cc = c0 + tx * 8 + j;
                if (s < minv[i]) { minv[i] = s; mini[i] = cc; }
            }
        }
#pragma unroll
        for (int i = 0; i < 4; ++i) {
#pragma unroll
            for (int off = 1; off < 16; off <<= 1) {
                float ov = __shfl_xor(minv[i], off);
                int   oi = __shfl_xor(mini[i], off);
                if (ov < minv[i] || (ov == minv[i] && oi < mini[i])) {
                    minv[i] = ov; mini[i] = oi;
                }
            }
        }
        if (tx == 0) {
#pragma unroll
            for (int i = 0; i < 4; ++i) {
                int pos = t0 + ty * 4 + i;
                if (pos < n) {
                    unsigned long long pu =
                        ((unsigned long long)(unsigned)__float_as_int(minv[i]) << 32)
                        | (unsigned)mini[i];
                    atomicMin(&pack[pos], pu);
                }
            }
        }
        __syncthreads();
    }
}

// ---- unpack cleanup results; delta-correct idx, float idx, and histogram
__global__ void cleanup_write(const unsigned* __restrict__ nflagp,
                              const int* __restrict__ flaglist,
                              const unsigned long long* __restrict__ pack,
                              int* __restrict__ idx_out, float* __restrict__ out,
                              unsigned* __restrict__ cnt) {
    int n = (int)nflagp[0];
    for (int i = blockIdx.x * 256 + threadIdx.x; i < n; i += 65536) {
        int t = flaglist[i];
        int code = (int)(pack[i] & 0xFFFFFFFFull);
        int old  = idx_out[t];
        if (code != old) {
            idx_out[t] = code;
            out[O_IDX + t] = (float)code;
            atomicAdd(&cnt[code], 1u);
            atomicAdd(&cnt[old], 0xFFFFFFFFu);   // -1
        }
    }
}

// ---- fused scan + scatter: each block redundantly computes the exclusive
// prefix of cnt in LDS (cheap, L2-hit), then scatters its 256 tokens via the
// global cursor. Block 0 also writes cntf for finalize_small.
__global__ __launch_bounds__(256) void k_scatter(
    const int* __restrict__ idx, const unsigned* __restrict__ cnt,
    unsigned* __restrict__ cursor, unsigned* __restrict__ order,
    float* __restrict__ cntf)
{
    __shared__ unsigned soffs[1024];
    __shared__ unsigned wsum[4];
    int t = threadIdx.x, lane = t & 63, wid = t >> 6;
    uint4 v = ((const uint4*)cnt)[t];
    if (blockIdx.x == 0) {
        cntf[4 * t + 0] = (float)v.x; cntf[4 * t + 1] = (float)v.y;
        cntf[4 * t + 2] = (float)v.z; cntf[4 * t + 3] = (float)v.w;
    }
    unsigned s = v.x + v.y + v.z + v.w;
    unsigned ps = s;
#pragma unroll
    for (int off = 1; off < 64; off <<= 1) {
        unsigned o = __shfl_up(ps, off);
        if (lane >= off) ps += o;
    }
    if (lane == 63) wsum[wid] = ps;
    __syncthreads();
    unsigned base = 0;
#pragma unroll
    for (int i = 0; i < 4; ++i) if (i < wid) base += wsum[i];
    unsigned excl = base + ps - s;
    soffs[4 * t + 0] = excl;
    soffs[4 * t + 1] = excl + v.x;
    soffs[4 * t + 2] = excl + v.x + v.y;
    soffs[4 * t + 3] = excl + v.x + v.y + v.z;
    __syncthreads();
    int tok = blockIdx.x * 256 + threadIdx.x;
    int c = idx[tok];
    unsigned p = atomicAdd(&cursor[c], 1u);
    order[soffs[c] + p] = ((unsigned)c << 16) | (unsigned)tok;
}

// ---- fused consumer over sorted order (R10-proven form): Q gather-write +
// e-loss + dw runs. 16 positions/wave, unroll 4, run-accumulated dw flushes.
__global__ __launch_bounds__(256) void k_epilogue_dw(
    const float* __restrict__ X, const float* __restrict__ W,
    const unsigned* __restrict__ order, float* __restrict__ out,
    float* __restrict__ dw, float* __restrict__ elat_arr)
{
    int gw   = (blockIdx.x * 256 + threadIdx.x) >> 6;   // 4096 waves
    int lane = threadIdx.x & 63;
    int p0 = gw * 16;
    float4 acc = make_float4(0.f, 0.f, 0.f, 0.f);
    float4 wreg = make_float4(0.f, 0.f, 0.f, 0.f);
    int cur = -1;
    float e = 0.f;
#pragma unroll 4
    for (int i = 0; i < 16; ++i) {
        unsigned u = order[p0 + i];
        int t = (int)(u & 0xFFFFu), c = (int)(u >> 16);
        float4 x4 = *(const float4*)(X + (size_t)t * 256 + lane * 4);
        if (c != cur) {                   // wave-uniform branch
            if (cur >= 0) {
                float* dwp = dw + (size_t)cur * 256 + lane * 4;
                atomicAdd(dwp + 0, acc.x); atomicAdd(dwp + 1, acc.y);
                atomicAdd(dwp + 2, acc.z); atomicAdd(dwp + 3, acc.w);
            }
            wreg = *(const float4*)(W + (size_t)c * 256 + lane * 4);
            cur = c; acc = x4;
        } else {
            acc.x += x4.x; acc.y += x4.y; acc.z += x4.z; acc.w += x4.w;
        }
        ((float4*)(out + O_Q))[(size_t)t * 64 + lane] = wreg;
        float d0 = wreg.x - x4.x, d1 = wreg.y - x4.y;
        float d2 = wreg.z - x4.z, d3 = wreg.w - x4.w;
        e += d0 * d0 + d1 * d1 + d2 * d2 + d3 * d3;
    }
    if (cur >= 0) {
        float* dwp = dw + (size_t)cur * 256 + lane * 4;
        atomicAdd(dwp + 0, acc.x); atomicAdd(dwp + 1, acc.y);
        atomicAdd(dwp + 2, acc.z); atomicAdd(dwp + 3, acc.w);
    }
#pragma unroll
    for (int off = 1; off < 64; off <<= 1) e += __shfl_xor(e, off);
    __shared__ float se[4];
    int wid = threadIdx.x >> 6;
    if (lane == 0) se[wid] = e;
    __syncthreads();
    if (threadIdx.x == 0) elat_arr[blockIdx.x] = se[0] + se[1] + se[2] + se[3];
}

// ------------------------------------------------ cluster EMA + loss + perplexity
__global__ __launch_bounds__(1024) void finalize_small(
    const float* __restrict__ ecs, const float* __restrict__ counts,
    const float* __restrict__ elat_arr, float* __restrict__ out)
{
    int k = threadIdx.x;
    float cnt = counts[k];
    float nc = ecs[k] * (1.0f - MU_C) + MU_C * cnt;
    float p = cnt * (1.0f / 65536.0f);
    float h = p * logf(p + 1e-10f);
    float el = elat_arr[k];               // 1024 per-block partials
    float rn = nc, rh = h, re = el;
#pragma unroll
    for (int off = 1; off < 64; off <<= 1) {
        rn += __shfl_xor(rn, off);
        rh += __shfl_xor(rh, off);
        re += __shfl_xor(re, off);
    }
    __shared__ float sn[16], sh[16], sef[16];
    int wid = k >> 6, lane = k & 63;
    if (lane == 0) { sn[wid] = rn; sh[wid] = rh; sef[wid] = re; }
    __syncthreads();
    float n = 0.0f, H = 0.0f, E = 0.0f;
#pragma unroll
    for (int i = 0; i < 16; ++i) { n += sn[i]; H += sh[i]; E += sef[i]; }
    out[O_NC + k] = (nc + EPS_C) / (n + 1024.0f * EPS_C) * n;
    if (k == 0) {
        out[O_LOSS] = 0.25f * (E * (1.0f / 16777216.0f));
        out[O_PERP] = expf(-H);
    }
}

// ------------------------------------------------ new_ema_w / new_embedding
__global__ void finalize_embed(const float* __restrict__ ema_w,
                               const float* __restrict__ dw, float* __restrict__ out)
{
    int gid = blockIdx.x * blockDim.x + threadIdx.x;   // < 262144
    int k = gid >> 8;
    float ew = ema_w[gid] * (1.0f - MU_C) + MU_C * dw[gid];
    out[O_NEW + gid] = ew;
    out[O_EMB + gid] = ew / out[O_NC + k];
}

extern "C" void kernel_launch(void* const* d_in, const int* in_sizes, int n_in,
                              void* d_out, int out_size, void* d_ws, size_t ws_size,
                              hipStream_t stream) {
    const float* X     = (const float*)d_in[0];
    const float* W     = (const float*)d_in[1];
    const float* ema_w = (const float*)d_in[2];
    const float* ecs   = (const float*)d_in[3];
    float*    out    = (float*)d_out;
    unsigned* wsu    = (unsigned*)d_ws;
    float*    wsf    = (float*)d_ws;
    int*      idx    = (int*)d_ws + W_IDX;
    unsigned* cnt    = wsu + W_CNT;
    unsigned* cursor = wsu + W_CUR;
    float*    cntf   = wsf + W_CNTF;
    unsigned* nflag  = wsu + W_NFLAG;
    int*      flags  = (int*)d_ws + W_FLAG;
    unsigned* order  = wsu + W_ORDER;
    float*    dw     = wsf + W_DW;
    float*    wsq    = wsf + W_WSQ;
    _Float16* Wh     = (_Float16*)(wsu + W_WH);
    float*    xsqf   = wsf + W_XSQF;
    float*    elatA  = wsf + W_ELATA;
    unsigned long long* pack    = (unsigned long long*)(wsu + W_PACK);
    unsigned long long* halfres = (unsigned long long*)(wsu + W_HALF);

    hipLaunchKernelGGL(k_init,         dim3(256),   dim3(256),  0, stream, W, Wh, wsq, wsu);
    hipLaunchKernelGGL(argmin_mfma,    dim3(512),   dim3(256),  0, stream, X, Wh, wsq, halfres);
    hipLaunchKernelGGL(merge_halves,   dim3(256),   dim3(256),  0, stream, halfres, idx, out, cnt, nflag, flags);
    hipLaunchKernelGGL(cleanup_xsq,    dim3(256),   dim3(256),  0, stream, X, nflag, flags, xsqf);
    hipLaunchKernelGGL(cleanup_gemm,   dim3(2048),  dim3(256),  0, stream, X, W, wsq, nflag, flags, xsqf, pack);
    hipLaunchKernelGGL(cleanup_write,  dim3(256),   dim3(256),  0, stream, nflag, flags, pack, idx, out, cnt);
    hipLaunchKernelGGL(k_scatter,      dim3(256),   dim3(256),  0, stream, idx, cnt, cursor, order, cntf);
    hipLaunchKernelGGL(k_epilogue_dw,  dim3(1024),  dim3(256),  0, stream, X, W, order, out, dw, elatA);
    hipLaunchKernelGGL(finalize_small, dim3(1),     dim3(1024), 0, stream, ecs, cntf, elatA, out);
    hipLaunchKernelGGL(finalize_embed, dim3(1024),  dim3(256),  0, stream, ema_w, dw, out);
}